// Round 9
// baseline (370.180 us; speedup 1.0000x reference)
//
#include <hip/hip_runtime.h>
#include <math.h>

#define BGR 64          // graphs
#define N0 512          // nodes/graph at level 1
#define E_TOT (BGR*N0*16)
#define EPG 8192        // edge slots per graph, fixed across levels
#define HID 128
#define LOFF2 32768     // rowptr/cnt/dinv offset for level-2 ids
#define LOFF3 49152     // level-3 ids

// XOR-swizzled [row][8 x float4] tile index: breaks the stride-32-float
// bank conflict on per-row float4 reads (validated in k_l1_fused).
#define HSW(r,l) (((r)<<3) | (((l)+(r))&7))
// 32-slot rotation for the [64][32 x float4] staging tile.
#define XST(r,q) (((r)<<5) | (((q)+(r))&31))

// hybrid shfl/LDS bitonic (descending, idx tie-break) — validated r0-r8
__device__ __forceinline__ void bitonic_sort(float* sv, int* si, float v, int idx,
                                             int t, int nper, bool act){
  for (int kk = 2; kk <= nper; kk <<= 1){
    for (int jj = kk >> 1; jj > 0; jj >>= 1){
      if (jj >= 64){
        if (act){ sv[t] = v; si[t] = idx; }
        __syncthreads();
        if (act){
          int p = t ^ jj;
          float pv = sv[p]; int pi = si[p];
          bool amLower = (t & jj) == 0;
          bool dirDesc = (t & kk) == 0;
          bool betterMine = (v > pv) || (v == pv && idx < pi);
          if ((amLower == dirDesc) != betterMine){ v = pv; idx = pi; }
        }
        __syncthreads();
      } else if (act){
        float pv = __shfl_xor(v, jj);
        int   pi = __shfl_xor(idx, jj);
        bool amLower = (t & jj) == 0;
        bool dirDesc = (t & kk) == 0;
        bool betterMine = (v > pv) || (v == pv && idx < pi);
        if ((amLower == dirDesc) != betterMine){ v = pv; idx = pi; }
      }
    }
  }
  if (act){ sv[t] = v; si[t] = idx; }
  __syncthreads();
}

// relabel at 1024 threads; edge list pre-loaded into registers (epre) so the
// L2 reads overlap score+sort. Next level topology -> [loff + ...].
__device__ __forceinline__ void relabel_pre(
    int2* __restrict__ edges, int2* __restrict__ csr, const int* si,
    int* map_, int* sb, int* cur, float* dl, int* wsum,
    int* __restrict__ rowptr, int* __restrict__ cnt, float* __restrict__ dinv,
    const int2* epre,
    int t, int nper, int k, int gbase, int gbnew, int ebase, int loff){
  if (t < nper) map_[t] = -1;
  if (t < k) sb[t] = 0;
  __syncthreads();
  if (t < k) map_[si[t]] = t;
  __syncthreads();
  int2 ebuf[8];
  #pragma unroll
  for (int it = 0; it < 8; it++){
    int2 e = epre[it];
    int2 ne = make_int2(-1, 0);
    if (e.x >= 0){
      int ns = map_[e.x - gbase], nd = map_[e.y - gbase];
      if (ns >= 0 && nd >= 0){
        ne = make_int2(gbnew + ns, gbnew + nd);
        atomicAdd(&sb[nd], 1);
      }
    }
    ebuf[it] = ne;
    edges[ebase + it*1024 + t] = ne;
  }
  __syncthreads();
  int vdeg = (t < k) ? sb[t] : 0;
  int lane = t & 63, wid = t >> 6;
  int x = vdeg;
  #pragma unroll
  for (int off = 1; off < 64; off <<= 1){
    int y = __shfl_up(x, off);
    if (lane >= off) x += y;
  }
  if (t < k && lane == 63) wsum[wid] = x;
  __syncthreads();
  if (t < k){
    int prefix = 0;
    #pragma unroll
    for (int wj = 0; wj < 4; wj++) prefix += (wj < wid) ? wsum[wj] : 0;
    int excl = x + prefix - vdeg;
    rowptr[loff + gbnew + t] = ebase + excl;
    cnt[loff + gbnew + t] = vdeg;
    cur[t] = excl;
    float dv = rsqrtf((float)vdeg + 1.f);
    dl[t] = dv;
    dinv[loff + gbnew + t] = dv;
  }
  __syncthreads();
  #pragma unroll
  for (int it = 0; it < 8; it++){
    int2 e = ebuf[it];
    if (e.x >= 0){
      int sl = e.x - gbnew, dc = e.y - gbnew;
      int pos = atomicAdd(&cur[dc], 1);
      csr[ebase + pos] = make_int2(e.x, __float_as_int(dl[sl]*dl[dc]));
    }
  }
  __syncthreads();
}

// Per-graph level-1 topology — 1024 threads (r8)
__global__ __launch_bounds__(1024) void k_topo0(
    const int* __restrict__ s0, const int* __restrict__ d0,
    int2* __restrict__ edges, int* __restrict__ cnt, int* __restrict__ rowptr,
    float* __restrict__ dinv, int2* __restrict__ csr){
  __shared__ int   deg[512];
  __shared__ int   cur[512];
  __shared__ float dl[512];
  __shared__ int   wsum[8];
  int g = (blockIdx.x & 7)*8 + (blockIdx.x >> 3);
  int t = threadIdx.x;
  int gbase = g*N0, ebase = g*EPG;
  if (t < 512) deg[t] = 0;
  __syncthreads();
  int2 ebuf[8];
  #pragma unroll
  for (int it = 0; it < 8; it++){
    int i = ebase + it*1024 + t;
    int2 e = make_int2(s0[i], d0[i]);
    ebuf[it] = e;
    edges[i] = e;
    atomicAdd(&deg[e.y - gbase], 1);
  }
  __syncthreads();
  int vdeg = (t < 512) ? deg[t] : 0;
  int lane = t & 63, wid = t >> 6;
  int x = vdeg;
  #pragma unroll
  for (int off = 1; off < 64; off <<= 1){
    int y = __shfl_up(x, off);
    if (lane >= off) x += y;
  }
  if (t < 512 && lane == 63) wsum[wid] = x;
  __syncthreads();
  if (t < 512){
    int prefix = 0;
    #pragma unroll
    for (int wj = 0; wj < 8; wj++) prefix += (wj < wid) ? wsum[wj] : 0;
    int excl = x + prefix - vdeg;
    rowptr[gbase + t] = ebase + excl;
    cnt[gbase + t] = vdeg;
    cur[t] = excl;
    float dv = rsqrtf((float)vdeg + 1.f);
    dl[t] = dv;
    dinv[gbase + t] = dv;
  }
  __syncthreads();
  #pragma unroll
  for (int it = 0; it < 8; it++){
    int2 e = ebuf[it];
    int sl = e.x - gbase, dc = e.y - gbase;
    int pos = atomicAdd(&cur[dc], 1);
    csr[ebase + pos] = make_int2(e.x, __float_as_int(dl[sl]*dl[dc]));
  }
}

// Level-1 fused GEMM+gather; hl tile XOR-swizzled (validated r4-r8).
__global__ __launch_bounds__(512) void k_l1_fused(
    const float* __restrict__ x, const float* __restrict__ W1,
    const int2* __restrict__ csr, const int* __restrict__ rowptr,
    const int* __restrict__ cnt, const float* __restrict__ dinv,
    const float* __restrict__ b1, const float* __restrict__ Wp,
    float4* __restrict__ gout4, float* __restrict__ hp_part){
  extern __shared__ float hl[];   // 512 nodes x 32 feats = 64 KB
  int b = blockIdx.x;
  int xcd = b & 7, idx = b >> 3;
  int graph = xcd*8 + (idx >> 3);
  int sub = idx & 7;
  int qf = sub >> 1, half = sub & 1;
  int t = threadIdx.x;
  int gbase = graph*N0;
  int fp = t & 31;
  int f = qf*32 + fp;
  float wcol[10];
  #pragma unroll
  for (int k = 0; k < 10; k++) wcol[k] = W1[k*HID + f];
  for (int n = t >> 5; n < N0; n += 16){
    const float* xr = x + (gbase + n)*10;
    float acc = 0.f;
    #pragma unroll
    for (int k = 0; k < 10; k++) acc += xr[k]*wcol[k];
    hl[n*32 + ((((fp>>2)+n)&7)<<2) + (fp&3)] = acc;
  }
  __syncthreads();
  const float4* hl4 = (const float4*)hl;
  int l = t & 7, grp = t >> 3;
  float4 bb = ((const float4*)b1)[qf*8 + l];
  float4 wp = ((const float4*)Wp)[qf*8 + l];
  int n0 = half*256;
  for (int nl = n0 + grp; nl < n0 + 256; nl += 64){
    int node = gbase + nl;
    int start = rowptr[node], c = cnt[node];
    float4 acc = make_float4(0.f,0.f,0.f,0.f);
    int j = 0;
    for (; j + 4 <= c; j += 4){
      int2 e0 = csr[start+j],   e1 = csr[start+j+1];
      int2 e2 = csr[start+j+2], e3 = csr[start+j+3];
      float4 h0 = hl4[HSW(e0.x - gbase, l)];
      float4 h1 = hl4[HSW(e1.x - gbase, l)];
      float4 h2 = hl4[HSW(e2.x - gbase, l)];
      float4 h3 = hl4[HSW(e3.x - gbase, l)];
      float w0 = __int_as_float(e0.y), w1 = __int_as_float(e1.y);
      float w2 = __int_as_float(e2.y), w3 = __int_as_float(e3.y);
      acc.x += w0*h0.x + w1*h1.x + w2*h2.x + w3*h3.x;
      acc.y += w0*h0.y + w1*h1.y + w2*h2.y + w3*h3.y;
      acc.z += w0*h0.z + w1*h1.z + w2*h2.z + w3*h3.z;
      acc.w += w0*h0.w + w1*h1.w + w2*h2.w + w3*h3.w;
    }
    for (; j < c; j++){
      int2 e = csr[start + j];
      float wgt = __int_as_float(e.y);
      float4 hv = hl4[HSW(e.x - gbase, l)];
      acc.x += wgt*hv.x; acc.y += wgt*hv.y; acc.z += wgt*hv.z; acc.w += wgt*hv.w;
    }
    float di = dinv[node], dd = di*di;
    float4 hs = hl4[HSW(nl, l)];
    float4 v;
    v.x = fmaxf(acc.x + hs.x*dd + bb.x, 0.f);
    v.y = fmaxf(acc.y + hs.y*dd + bb.y, 0.f);
    v.z = fmaxf(acc.z + hs.z*dd + bb.z, 0.f);
    v.w = fmaxf(acc.w + hs.w*dd + bb.w, 0.f);
    gout4[node*32 + qf*8 + l] = v;
    float contrib = v.x*wp.x + v.y*wp.y + v.z*wp.z + v.w*wp.w;
    #pragma unroll
    for (int off = 4; off; off >>= 1) contrib += __shfl_down(contrib, off, 8);
    if (l == 0) hp_part[qf*32768 + node] = contrib;
  }
}

// mega1: score+sort over level-1, z store, si/sv export, relabel -> LOFF2.
__global__ __launch_bounds__(1024) void k_mega1(
    const float4* __restrict__ gout4, const float* __restrict__ hppt,
    int2* __restrict__ csr, int* __restrict__ rowptr, int* __restrict__ cnt,
    float* __restrict__ dinv, const float* __restrict__ bp,
    int2* __restrict__ edges, int* __restrict__ sig, float* __restrict__ svg,
    float* __restrict__ z){
  __shared__ float sv[512];
  __shared__ int   si[512];
  __shared__ float hpl[512];
  __shared__ union UA {
    float spart[1024];
    struct { float4 pmx[32][32]; float4 psm[32][32]; } ro;
    struct { int map_[512]; int sb[512]; int cur[256]; } rl;
  } u;
  __shared__ float dl[256];
  __shared__ int   wsum[4];
  int g = (blockIdx.x & 7)*8 + (blockIdx.x >> 3);
  int t = threadIdx.x;
  int gbase = g*N0, ebase = g*EPG, gb2 = g*256;
  float bp0 = bp[0];
  int2 epre[8];
  #pragma unroll
  for (int it = 0; it < 8; it++) epre[it] = edges[ebase + it*1024 + t];
  if (t < 512){
    int node = gbase + t;
    hpl[t] = hppt[node] + hppt[32768+node] + hppt[65536+node] + hppt[98304+node];
  }
  __syncthreads();
  {  // split score, SPL=2
    int n = t & 511, p = t >> 9;
    int start = rowptr[gbase + n], c = cnt[gbase + n];
    int lo = (c*p) >> 1, hi = (c*(p+1)) >> 1;
    float a = 0.f;
    for (int j = lo; j < hi; j++){
      int2 e = csr[start + j];
      a += __int_as_float(e.y)*hpl[e.x - gbase];
    }
    u.spart[t] = a;
  }
  __syncthreads();
  float v = 0.f; int idx = t;
  if (t < 512){
    float a = u.spart[t] + u.spart[t + 512];
    float di = dinv[gbase + t];
    v = tanhf(a + hpl[t]*di*di + bp0);
  }
  __syncthreads();
  bitonic_sort(sv, si, v, idx, t, 512, t < 512);
  if (t < 256){ sig[g*512 + t] = si[t]; svg[g*512 + t] = sv[t]; }
  int l = t & 31, j0 = t >> 5;
  {
    float4 mx = make_float4(-INFINITY,-INFINITY,-INFINITY,-INFINITY);
    float4 sm = make_float4(0.f,0.f,0.f,0.f);
    for (int j = j0; j < 256; j += 32){
      float val = sv[j]; int row = si[j];
      float4 hv = gout4[(gbase + row)*32 + l];
      float4 o = make_float4(hv.x*val, hv.y*val, hv.z*val, hv.w*val);
      mx.x = fmaxf(mx.x, o.x); mx.y = fmaxf(mx.y, o.y);
      mx.z = fmaxf(mx.z, o.z); mx.w = fmaxf(mx.w, o.w);
      sm.x += o.x; sm.y += o.y; sm.z += o.z; sm.w += o.w;
    }
    u.ro.pmx[j0][l] = mx; u.ro.psm[j0][l] = sm;
  }
  __syncthreads();
  if (t < 32){
    float4 M = u.ro.pmx[0][t], S = u.ro.psm[0][t];
    #pragma unroll
    for (int q = 1; q < 32; q++){
      float4 m2 = u.ro.pmx[q][t], s2 = u.ro.psm[q][t];
      M.x = fmaxf(M.x, m2.x); M.y = fmaxf(M.y, m2.y);
      M.z = fmaxf(M.z, m2.z); M.w = fmaxf(M.w, m2.w);
      S.x += s2.x; S.y += s2.y; S.z += s2.z; S.w += s2.w;
    }
    float ki = 1.f/256.f;
    float* zp = z + g*256;
    zp[t*4+0] = M.x; zp[t*4+1] = M.y; zp[t*4+2] = M.z; zp[t*4+3] = M.w;
    zp[128+t*4+0] = S.x*ki; zp[128+t*4+1] = S.y*ki;
    zp[128+t*4+2] = S.z*ki; zp[128+t*4+3] = S.w*ki;
  }
  __syncthreads();
  relabel_pre(edges, csr, si, u.rl.map_, u.rl.sb, u.rl.cur, dl, wsum,
              rowptr, cnt, dinv, epre, t, 512, 256, gbase, gb2, ebase, LOFF2);
}

// k_lvl2: feature-split, 4 blocks/graph, NO GEMM duplication. Pooled rows
// staged through LDS in 64-row chunks (coalesced global, conflict-free LDS)
// before the slice GEMM; gather over all 256 nodes from the HSW h-tile.
__global__ __launch_bounds__(512) void k_lvl2(
    const float4* __restrict__ gout4,
    const int* __restrict__ sig, const float* __restrict__ svg,
    const float* __restrict__ W2, const float* __restrict__ b2,
    const float* __restrict__ Wp,
    const int2* __restrict__ csr, const int* __restrict__ rowptr,
    const int* __restrict__ cnt, const float* __restrict__ dinv,
    float4* __restrict__ g2out4, float* __restrict__ hp2p){
  __shared__ float xst[64*HID];   // 32 KB staged pooled rows (XST swizzle)
  __shared__ float hL[256*32];    // 32 KB slice out tile (HSW swizzle)
  int b = blockIdx.x;
  int jb = b & 63, s = b >> 6;
  int g = (jb & 7)*8 + (jb >> 3);
  int t = threadIdx.x;
  int gbase = g*N0, gb2 = g*256;
  float4* hL4 = (float4*)hL;
  float4* xst4 = (float4*)xst;
  int f4 = t & 7, rg = t >> 3;          // rg in [0,64)
  const float* Wb = W2 + s*32 + f4*4;
  for (int c0 = 0; c0 < 256; c0 += 64){
    {  // stage 64 pooled rows, scaled by sv (same product order as before)
      int row = t >> 3;
      int q0 = (t & 7)*4;
      int pr = c0 + row;
      int ri = sig[g*512 + pr];
      float rv = svg[g*512 + pr];
      const float4* src = gout4 + (gbase + ri)*32;
      #pragma unroll
      for (int q = 0; q < 4; q++){
        float4 a = src[q0 + q];
        xst4[XST(row, q0 + q)] = make_float4(a.x*rv, a.y*rv, a.z*rv, a.w*rv);
      }
    }
    __syncthreads();
    {  // GEMM chunk: thread (f4, rg) computes row c0+rg, 4 feats
      float4 acc = make_float4(0.f,0.f,0.f,0.f);
      for (int i = 0; i < HID; i += 4){
        float4 w0 = *(const float4*)(Wb + (i+0)*HID);
        float4 w1 = *(const float4*)(Wb + (i+1)*HID);
        float4 w2 = *(const float4*)(Wb + (i+2)*HID);
        float4 w3 = *(const float4*)(Wb + (i+3)*HID);
        float4 xv = xst4[XST(rg, i>>2)];
        acc.x += xv.x*w0.x + xv.y*w1.x + xv.z*w2.x + xv.w*w3.x;
        acc.y += xv.x*w0.y + xv.y*w1.y + xv.z*w2.y + xv.w*w3.y;
        acc.z += xv.x*w0.z + xv.y*w1.z + xv.z*w2.z + xv.w*w3.z;
        acc.w += xv.x*w0.w + xv.y*w1.w + xv.z*w2.w + xv.w*w3.w;
      }
      hL4[HSW(c0 + rg, f4)] = acc;
    }
    __syncthreads();
  }
  int l = t & 7, grpn = t >> 3;
  float4 bb = ((const float4*)b2)[s*8 + l];
  float4 wp = ((const float4*)Wp)[s*8 + l];
  for (int it = 0; it < 4; it++){
    int n = it*64 + grpn;
    int node = gb2 + n;
    int start = rowptr[LOFF2 + node], c = cnt[LOFF2 + node];
    float4 acc = make_float4(0.f,0.f,0.f,0.f);
    int j = 0;
    for (; j + 4 <= c; j += 4){
      int2 e0 = csr[start+j],   e1 = csr[start+j+1];
      int2 e2 = csr[start+j+2], e3 = csr[start+j+3];
      float4 h0 = hL4[HSW(e0.x - gb2, l)];
      float4 h1 = hL4[HSW(e1.x - gb2, l)];
      float4 h2 = hL4[HSW(e2.x - gb2, l)];
      float4 h3 = hL4[HSW(e3.x - gb2, l)];
      float w0 = __int_as_float(e0.y), w1 = __int_as_float(e1.y);
      float w2 = __int_as_float(e2.y), w3 = __int_as_float(e3.y);
      acc.x += w0*h0.x + w1*h1.x + w2*h2.x + w3*h3.x;
      acc.y += w0*h0.y + w1*h1.y + w2*h2.y + w3*h3.y;
      acc.z += w0*h0.z + w1*h1.z + w2*h2.z + w3*h3.z;
      acc.w += w0*h0.w + w1*h1.w + w2*h2.w + w3*h3.w;
    }
    for (; j < c; j++){
      int2 e = csr[start + j];
      float wgt = __int_as_float(e.y);
      float4 hv = hL4[HSW(e.x - gb2, l)];
      acc.x += wgt*hv.x; acc.y += wgt*hv.y; acc.z += wgt*hv.z; acc.w += wgt*hv.w;
    }
    float di = dinv[LOFF2 + node], dd = di*di;
    float4 hs = hL4[HSW(n, l)];
    float4 v;
    v.x = fmaxf(acc.x + hs.x*dd + bb.x, 0.f);
    v.y = fmaxf(acc.y + hs.y*dd + bb.y, 0.f);
    v.z = fmaxf(acc.z + hs.z*dd + bb.z, 0.f);
    v.w = fmaxf(acc.w + hs.w*dd + bb.w, 0.f);
    g2out4[node*32 + s*8 + l] = v;
    float contrib = v.x*wp.x + v.y*wp.y + v.z*wp.z + v.w*wp.w;
    #pragma unroll
    for (int off = 4; off; off >>= 1) contrib += __shfl_down(contrib, off, 8);
    if (l == 0) hp2p[s*16384 + node] = contrib;
  }
}

// mega2: score+sort over level-2, z accumulate, si/sv export, relabel -> LOFF3.
__global__ __launch_bounds__(1024) void k_mega2(
    const float4* __restrict__ g2out4, const float* __restrict__ hp2p,
    int2* __restrict__ csr, int* __restrict__ rowptr, int* __restrict__ cnt,
    float* __restrict__ dinv, const float* __restrict__ bp,
    int2* __restrict__ edges, int* __restrict__ sig, float* __restrict__ svg,
    float* __restrict__ z){
  __shared__ float sv[256];
  __shared__ int   si[256];
  __shared__ float hpl[256];
  __shared__ union UB {
    float spart[1024];
    struct { float4 pmx[32][32]; float4 psm[32][32]; } ro;
    struct { int map_[256]; int sb[128]; int cur[128]; } rl;
  } u;
  __shared__ float dl[128];
  __shared__ int   wsum[4];
  int g = (blockIdx.x & 7)*8 + (blockIdx.x >> 3);
  int t = threadIdx.x;
  int gb2 = g*256, gb3 = g*128, ebase = g*EPG;
  float bp0 = bp[0];
  int2 epre[8];
  #pragma unroll
  for (int it = 0; it < 8; it++) epre[it] = edges[ebase + it*1024 + t];
  if (t < 256){
    int node = gb2 + t;
    hpl[t] = hp2p[node] + hp2p[16384+node] + hp2p[32768+node] + hp2p[49152+node];
  }
  __syncthreads();
  {  // split score, SPL=4
    int n = t & 255, p = t >> 8;
    int start = rowptr[LOFF2 + gb2 + n], c = cnt[LOFF2 + gb2 + n];
    int lo = (c*p) >> 2, hi = (c*(p+1)) >> 2;
    float a = 0.f;
    for (int j = lo; j < hi; j++){
      int2 e = csr[start + j];
      a += __int_as_float(e.y)*hpl[e.x - gb2];
    }
    u.spart[t] = a;
  }
  __syncthreads();
  float v = 0.f; int idx = t;
  if (t < 256){
    float a = u.spart[t] + u.spart[t+256] + u.spart[t+512] + u.spart[t+768];
    float di = dinv[LOFF2 + gb2 + t];
    v = tanhf(a + hpl[t]*di*di + bp0);
  }
  __syncthreads();
  bitonic_sort(sv, si, v, idx, t, 256, t < 256);
  if (t < 128){ sig[g*512 + t] = si[t]; svg[g*512 + t] = sv[t]; }
  int l = t & 31, j0 = t >> 5;
  {
    float4 mx = make_float4(-INFINITY,-INFINITY,-INFINITY,-INFINITY);
    float4 sm = make_float4(0.f,0.f,0.f,0.f);
    for (int j = j0; j < 128; j += 32){
      float val = sv[j]; int row = si[j];
      float4 hv = g2out4[(gb2 + row)*32 + l];
      float4 o = make_float4(hv.x*val, hv.y*val, hv.z*val, hv.w*val);
      mx.x = fmaxf(mx.x, o.x); mx.y = fmaxf(mx.y, o.y);
      mx.z = fmaxf(mx.z, o.z); mx.w = fmaxf(mx.w, o.w);
      sm.x += o.x; sm.y += o.y; sm.z += o.z; sm.w += o.w;
    }
    u.ro.pmx[j0][l] = mx; u.ro.psm[j0][l] = sm;
  }
  __syncthreads();
  if (t < 32){
    float4 M = u.ro.pmx[0][t], S = u.ro.psm[0][t];
    #pragma unroll
    for (int q = 1; q < 32; q++){
      float4 m2 = u.ro.pmx[q][t], s2 = u.ro.psm[q][t];
      M.x = fmaxf(M.x, m2.x); M.y = fmaxf(M.y, m2.y);
      M.z = fmaxf(M.z, m2.z); M.w = fmaxf(M.w, m2.w);
      S.x += s2.x; S.y += s2.y; S.z += s2.z; S.w += s2.w;
    }
    float ki = 1.f/128.f;
    float* zp = z + g*256;
    zp[t*4+0] += M.x; zp[t*4+1] += M.y; zp[t*4+2] += M.z; zp[t*4+3] += M.w;
    zp[128+t*4+0] += S.x*ki; zp[128+t*4+1] += S.y*ki;
    zp[128+t*4+2] += S.z*ki; zp[128+t*4+3] += S.w*ki;
  }
  __syncthreads();
  relabel_pre(edges, csr, si, u.rl.map_, u.rl.sb, u.rl.cur, dl, wsum,
              rowptr, cnt, dinv, epre, t, 256, 128, gb2, gb3, ebase, LOFF3);
}

// k_lvl3: feature-split, 4 blocks/graph, staged GEMM (2 chunks of 64 rows),
// gather all 128 nodes.
__global__ __launch_bounds__(512) void k_lvl3(
    const float4* __restrict__ g2out4,
    const int* __restrict__ sig, const float* __restrict__ svg,
    const float* __restrict__ W3, const float* __restrict__ b3,
    const float* __restrict__ Wp,
    const int2* __restrict__ csr, const int* __restrict__ rowptr,
    const int* __restrict__ cnt, const float* __restrict__ dinv,
    float4* __restrict__ g3out4, float* __restrict__ hp3p){
  __shared__ float xst[64*HID];   // 32 KB staged pooled rows
  __shared__ float hL[128*32];    // 16 KB slice out tile
  int b = blockIdx.x;
  int jb = b & 63, s = b >> 6;
  int g = (jb & 7)*8 + (jb >> 3);
  int t = threadIdx.x;
  int gb2 = g*256, gb3 = g*128;
  float4* hL4 = (float4*)hL;
  float4* xst4 = (float4*)xst;
  int f4 = t & 7, rg = t >> 3;
  const float* Wb = W3 + s*32 + f4*4;
  for (int c0 = 0; c0 < 128; c0 += 64){
    {
      int row = t >> 3;
      int q0 = (t & 7)*4;
      int pr = c0 + row;
      int ri = sig[g*512 + pr];
      float rv = svg[g*512 + pr];
      const float4* src = g2out4 + (gb2 + ri)*32;
      #pragma unroll
      for (int q = 0; q < 4; q++){
        float4 a = src[q0 + q];
        xst4[XST(row, q0 + q)] = make_float4(a.x*rv, a.y*rv, a.z*rv, a.w*rv);
      }
    }
    __syncthreads();
    {
      float4 acc = make_float4(0.f,0.f,0.f,0.f);
      for (int i = 0; i < HID; i += 4){
        float4 w0 = *(const float4*)(Wb + (i+0)*HID);
        float4 w1 = *(const float4*)(Wb + (i+1)*HID);
        float4 w2 = *(const float4*)(Wb + (i+2)*HID);
        float4 w3 = *(const float4*)(Wb + (i+3)*HID);
        float4 xv = xst4[XST(rg, i>>2)];
        acc.x += xv.x*w0.x + xv.y*w1.x + xv.z*w2.x + xv.w*w3.x;
        acc.y += xv.x*w0.y + xv.y*w1.y + xv.z*w2.y + xv.w*w3.y;
        acc.z += xv.x*w0.z + xv.y*w1.z + xv.z*w2.z + xv.w*w3.z;
        acc.w += xv.x*w0.w + xv.y*w1.w + xv.z*w2.w + xv.w*w3.w;
      }
      hL4[HSW(c0 + rg, f4)] = acc;
    }
    __syncthreads();
  }
  int l = t & 7, grpn = t >> 3;
  float4 bb = ((const float4*)b3)[s*8 + l];
  float4 wp = ((const float4*)Wp)[s*8 + l];
  for (int it = 0; it < 2; it++){
    int n = it*64 + grpn;
    int node = gb3 + n;
    int start = rowptr[LOFF3 + node], c = cnt[LOFF3 + node];
    float4 acc = make_float4(0.f,0.f,0.f,0.f);
    int j = 0;
    for (; j + 4 <= c; j += 4){
      int2 e0 = csr[start+j],   e1 = csr[start+j+1];
      int2 e2 = csr[start+j+2], e3 = csr[start+j+3];
      float4 h0 = hL4[HSW(e0.x - gb3, l)];
      float4 h1 = hL4[HSW(e1.x - gb3, l)];
      float4 h2 = hL4[HSW(e2.x - gb3, l)];
      float4 h3 = hL4[HSW(e3.x - gb3, l)];
      float w0 = __int_as_float(e0.y), w1 = __int_as_float(e1.y);
      float w2 = __int_as_float(e2.y), w3 = __int_as_float(e3.y);
      acc.x += w0*h0.x + w1*h1.x + w2*h2.x + w3*h3.x;
      acc.y += w0*h0.y + w1*h1.y + w2*h2.y + w3*h3.y;
      acc.z += w0*h0.z + w1*h1.z + w2*h2.z + w3*h3.z;
      acc.w += w0*h0.w + w1*h1.w + w2*h2.w + w3*h3.w;
    }
    for (; j < c; j++){
      int2 e = csr[start + j];
      float wgt = __int_as_float(e.y);
      float4 hv = hL4[HSW(e.x - gb3, l)];
      acc.x += wgt*hv.x; acc.y += wgt*hv.y; acc.z += wgt*hv.z; acc.w += wgt*hv.w;
    }
    float di = dinv[LOFF3 + node], dd = di*di;
    float4 hs = hL4[HSW(n, l)];
    float4 v;
    v.x = fmaxf(acc.x + hs.x*dd + bb.x, 0.f);
    v.y = fmaxf(acc.y + hs.y*dd + bb.y, 0.f);
    v.z = fmaxf(acc.z + hs.z*dd + bb.z, 0.f);
    v.w = fmaxf(acc.w + hs.w*dd + bb.w, 0.f);
    g3out4[node*32 + s*8 + l] = v;
    float contrib = v.x*wp.x + v.y*wp.y + v.z*wp.z + v.w*wp.w;
    #pragma unroll
    for (int off = 4; off; off >>= 1) contrib += __shfl_down(contrib, off, 8);
    if (l == 0) hp3p[s*8192 + node] = contrib;
  }
}

// mega3: score+sort over level-3, readout finalize + MLP + log_softmax.
__global__ __launch_bounds__(1024) void k_mega3(
    const float4* __restrict__ g3out4, const float* __restrict__ hp3p,
    const int2* __restrict__ csr, const int* __restrict__ rowptr,
    const int* __restrict__ cnt, const float* __restrict__ dinv,
    const float* __restrict__ bp, float* __restrict__ z,
    const float* __restrict__ L1W, const float* __restrict__ L1b,
    const float* __restrict__ L2W, const float* __restrict__ L2b,
    float* __restrict__ out){
  __shared__ float sv[128];
  __shared__ int   si[128];
  __shared__ float hpl[128];
  __shared__ union UC {
    float spart[1024];
    struct { float4 pmx[32][32]; float4 psm[32][32]; } ro;
  } u;
  __shared__ float zr[256];
  __shared__ float h1l[128];
  __shared__ float h2l[64];
  __shared__ float red[2];
  int g = (blockIdx.x & 7)*8 + (blockIdx.x >> 3);
  int t = threadIdx.x;
  int gb3 = g*128;
  float bp0 = bp[0];
  if (t < 128){
    int node = gb3 + t;
    hpl[t] = hp3p[node] + hp3p[8192+node] + hp3p[16384+node] + hp3p[24576+node];
  }
  __syncthreads();
  {  // split score, SPL=8
    int n = t & 127, p = t >> 7;
    int start = rowptr[LOFF3 + gb3 + n], c = cnt[LOFF3 + gb3 + n];
    int lo = (c*p) >> 3, hi = (c*(p+1)) >> 3;
    float a = 0.f;
    for (int j = lo; j < hi; j++){
      int2 e = csr[start + j];
      a += __int_as_float(e.y)*hpl[e.x - gb3];
    }
    u.spart[t] = a;
  }
  __syncthreads();
  float v = 0.f; int idx = t;
  if (t < 128){
    float a = 0.f;
    #pragma unroll
    for (int pp = 0; pp < 8; pp++) a += u.spart[t + pp*128];
    float di = dinv[LOFF3 + gb3 + t];
    v = tanhf(a + hpl[t]*di*di + bp0);
  }
  __syncthreads();
  bitonic_sort(sv, si, v, idx, t, 128, t < 128);
  int l = t & 31, j0 = t >> 5;
  {
    float4 mx = make_float4(-INFINITY,-INFINITY,-INFINITY,-INFINITY);
    float4 sm = make_float4(0.f,0.f,0.f,0.f);
    for (int j = j0; j < 64; j += 32){
      float val = sv[j]; int row = si[j];
      float4 hv = g3out4[(gb3 + row)*32 + l];
      float4 o = make_float4(hv.x*val, hv.y*val, hv.z*val, hv.w*val);
      mx.x = fmaxf(mx.x, o.x); mx.y = fmaxf(mx.y, o.y);
      mx.z = fmaxf(mx.z, o.z); mx.w = fmaxf(mx.w, o.w);
      sm.x += o.x; sm.y += o.y; sm.z += o.z; sm.w += o.w;
    }
    u.ro.pmx[j0][l] = mx; u.ro.psm[j0][l] = sm;
  }
  __syncthreads();
  if (t < 32){
    float4 M = u.ro.pmx[0][t], S = u.ro.psm[0][t];
    #pragma unroll
    for (int q = 1; q < 32; q++){
      float4 m2 = u.ro.pmx[q][t], s2 = u.ro.psm[q][t];
      M.x = fmaxf(M.x, m2.x); M.y = fmaxf(M.y, m2.y);
      M.z = fmaxf(M.z, m2.z); M.w = fmaxf(M.w, m2.w);
      S.x += s2.x; S.y += s2.y; S.z += s2.z; S.w += s2.w;
    }
    float ki = 1.f/64.f;
    float* zp = z + g*256;
    zr[t*4+0] = zp[t*4+0] + M.x; zr[t*4+1] = zp[t*4+1] + M.y;
    zr[t*4+2] = zp[t*4+2] + M.z; zr[t*4+3] = zp[t*4+3] + M.w;
    zr[128+t*4+0] = zp[128+t*4+0] + S.x*ki;
    zr[128+t*4+1] = zp[128+t*4+1] + S.y*ki;
    zr[128+t*4+2] = zp[128+t*4+2] + S.z*ki;
    zr[128+t*4+3] = zp[128+t*4+3] + S.w*ki;
  }
  __syncthreads();
  if (t < 128){
    float a = L1b[t];
    for (int i = 0; i < 256; i++) a += zr[i]*L1W[i*128 + t];
    h1l[t] = fmaxf(a, 0.f);
  }
  __syncthreads();
  if (t < 64){
    float a = L2b[t];
    for (int i = 0; i < 128; i++) a += h1l[i]*L2W[i*64 + t];
    h2l[t] = fmaxf(a, 0.f);
  }
  __syncthreads();
  if (t == 0){
    float mxv = -INFINITY;
    for (int i = 0; i < 64; i++) mxv = fmaxf(mxv, h2l[i]);
    float s = 0.f;
    for (int i = 0; i < 64; i++) s += expf(h2l[i] - mxv);
    red[0] = mxv; red[1] = logf(s);
  }
  __syncthreads();
  if (t < 64) out[g*64 + t] = h2l[t] - red[0] - red[1];
}

extern "C" void kernel_launch(void* const* d_in, const int* in_sizes, int n_in,
                              void* d_out, int out_size, void* d_ws, size_t ws_size,
                              hipStream_t stream){
  (void)in_sizes; (void)n_in; (void)out_size; (void)ws_size;
  const float* x0  = (const float*)d_in[0];
  const int*   s0  = (const int*)  d_in[1];
  const int*   d0  = (const int*)  d_in[2];
  const float* W1  = (const float*)d_in[3];  const float* b1 = (const float*)d_in[4];
  const float* W2  = (const float*)d_in[5];  const float* b2 = (const float*)d_in[6];
  const float* W3  = (const float*)d_in[7];  const float* b3 = (const float*)d_in[8];
  const float* Wp  = (const float*)d_in[9];  const float* bp = (const float*)d_in[10];
  const float* L1W = (const float*)d_in[11]; const float* L1b = (const float*)d_in[12];
  const float* L2W = (const float*)d_in[13]; const float* L2b = (const float*)d_in[14];
  float* out = (float*)d_out;

  // workspace layout (elements)
  float* w = (float*)d_ws;
  float* gout1 = w; w += 32768*HID;          // level-1 GCN output
  float* gout2 = w; w += 16384*HID;          // level-2 GCN output
  float* gout3 = w; w += 8192*HID;           // level-3 GCN output
  float* dinvv = w; w += 65536;              // levels via LOFF
  float* hppt  = w; w += 4*32768;            // L1 hp quarter-partials
  float* hp2p  = w; w += 4*16384;            // L2 hp slice-partials
  float* hp3p  = w; w += 4*8192;             // L3 hp slice-partials
  float* z     = w; w += BGR*256;
  float* svg   = w; w += 32768;
  int* sig     = (int*)w; w += 32768;
  int* cnt     = (int*)w; w += 65536;
  int* rowptr  = (int*)w; w += 65536;
  int2* edges  = (int2*)w; w += 2*E_TOT;
  int2* csr    = (int2*)w; w += 2*E_TOT;

  k_topo0<<<BGR, 1024, 0, stream>>>(s0, d0, edges, cnt, rowptr, dinvv, csr);
  k_l1_fused<<<512, 512, 65536, stream>>>(x0, W1, csr, rowptr, cnt, dinvv,
                                          b1, Wp, (float4*)gout1, hppt);
  k_mega1<<<BGR, 1024, 0, stream>>>((const float4*)gout1, hppt, csr, rowptr,
                                    cnt, dinvv, bp, edges, sig, svg, z);
  k_lvl2<<<4*BGR, 512, 0, stream>>>((const float4*)gout1, sig, svg, W2, b2, Wp,
                                    csr, rowptr, cnt, dinvv,
                                    (float4*)gout2, hp2p);
  k_mega2<<<BGR, 1024, 0, stream>>>((const float4*)gout2, hp2p, csr, rowptr,
                                    cnt, dinvv, bp, edges, sig, svg, z);
  k_lvl3<<<4*BGR, 512, 0, stream>>>((const float4*)gout2, sig, svg, W3, b3, Wp,
                                    csr, rowptr, cnt, dinvv,
                                    (float4*)gout3, hp3p);
  k_mega3<<<BGR, 1024, 0, stream>>>((const float4*)gout3, hp3p, csr, rowptr,
                                    cnt, dinvv, bp, z,
                                    L1W, L1b, L2W, L2b, out);
}

// Round 10
// 227.609 us; speedup vs baseline: 1.6264x; 1.6264x over previous
//
#include <hip/hip_runtime.h>
#include <math.h>

#define BGR 64          // graphs
#define N0 512          // nodes/graph at level 1
#define E_TOT (BGR*N0*16)
#define EPG 8192        // edge slots per graph, fixed across levels
#define HID 128
#define LOFF2 32768     // rowptr/cnt/dinv offset for level-2 ids
#define LOFF3 49152     // level-3 ids

// XOR-swizzled [row][8 x float4] tile index: breaks the stride-32-float
// bank conflict on per-row float4 reads (validated in k_l1_fused).
#define HSW(r,l) (((r)<<3) | (((l)+(r))&7))

// hybrid shfl/LDS bitonic (descending, idx tie-break) — validated r0-r9
__device__ __forceinline__ void bitonic_sort(float* sv, int* si, float v, int idx,
                                             int t, int nper, bool act){
  for (int kk = 2; kk <= nper; kk <<= 1){
    for (int jj = kk >> 1; jj > 0; jj >>= 1){
      if (jj >= 64){
        if (act){ sv[t] = v; si[t] = idx; }
        __syncthreads();
        if (act){
          int p = t ^ jj;
          float pv = sv[p]; int pi = si[p];
          bool amLower = (t & jj) == 0;
          bool dirDesc = (t & kk) == 0;
          bool betterMine = (v > pv) || (v == pv && idx < pi);
          if ((amLower == dirDesc) != betterMine){ v = pv; idx = pi; }
        }
        __syncthreads();
      } else if (act){
        float pv = __shfl_xor(v, jj);
        int   pi = __shfl_xor(idx, jj);
        bool amLower = (t & jj) == 0;
        bool dirDesc = (t & kk) == 0;
        bool betterMine = (v > pv) || (v == pv && idx < pi);
        if ((amLower == dirDesc) != betterMine){ v = pv; idx = pi; }
      }
    }
  }
  if (act){ sv[t] = v; si[t] = idx; }
  __syncthreads();
}

// relabel at 1024 threads; edge list pre-loaded into registers (epre) so the
// L2 reads overlap score+sort. Next level topology -> [loff + ...].
__device__ __forceinline__ void relabel_pre(
    int2* __restrict__ edges, int2* __restrict__ csr, const int* si,
    int* map_, int* sb, int* cur, float* dl, int* wsum,
    int* __restrict__ rowptr, int* __restrict__ cnt, float* __restrict__ dinv,
    const int2* epre,
    int t, int nper, int k, int gbase, int gbnew, int ebase, int loff){
  if (t < nper) map_[t] = -1;
  if (t < k) sb[t] = 0;
  __syncthreads();
  if (t < k) map_[si[t]] = t;
  __syncthreads();
  int2 ebuf[8];
  #pragma unroll
  for (int it = 0; it < 8; it++){
    int2 e = epre[it];
    int2 ne = make_int2(-1, 0);
    if (e.x >= 0){
      int ns = map_[e.x - gbase], nd = map_[e.y - gbase];
      if (ns >= 0 && nd >= 0){
        ne = make_int2(gbnew + ns, gbnew + nd);
        atomicAdd(&sb[nd], 1);
      }
    }
    ebuf[it] = ne;
    edges[ebase + it*1024 + t] = ne;
  }
  __syncthreads();
  int vdeg = (t < k) ? sb[t] : 0;
  int lane = t & 63, wid = t >> 6;
  int x = vdeg;
  #pragma unroll
  for (int off = 1; off < 64; off <<= 1){
    int y = __shfl_up(x, off);
    if (lane >= off) x += y;
  }
  if (t < k && lane == 63) wsum[wid] = x;
  __syncthreads();
  if (t < k){
    int prefix = 0;
    #pragma unroll
    for (int wj = 0; wj < 4; wj++) prefix += (wj < wid) ? wsum[wj] : 0;
    int excl = x + prefix - vdeg;
    rowptr[loff + gbnew + t] = ebase + excl;
    cnt[loff + gbnew + t] = vdeg;
    cur[t] = excl;
    float dv = rsqrtf((float)vdeg + 1.f);
    dl[t] = dv;
    dinv[loff + gbnew + t] = dv;
  }
  __syncthreads();
  #pragma unroll
  for (int it = 0; it < 8; it++){
    int2 e = ebuf[it];
    if (e.x >= 0){
      int sl = e.x - gbnew, dc = e.y - gbnew;
      int pos = atomicAdd(&cur[dc], 1);
      csr[ebase + pos] = make_int2(e.x, __float_as_int(dl[sl]*dl[dc]));
    }
  }
  __syncthreads();
}

// Per-graph level-1 topology — 1024 threads (validated r8: part of the
// net-positive tweak set)
__global__ __launch_bounds__(1024) void k_topo0(
    const int* __restrict__ s0, const int* __restrict__ d0,
    int2* __restrict__ edges, int* __restrict__ cnt, int* __restrict__ rowptr,
    float* __restrict__ dinv, int2* __restrict__ csr){
  __shared__ int   deg[512];
  __shared__ int   cur[512];
  __shared__ float dl[512];
  __shared__ int   wsum[8];
  int g = (blockIdx.x & 7)*8 + (blockIdx.x >> 3);
  int t = threadIdx.x;
  int gbase = g*N0, ebase = g*EPG;
  if (t < 512) deg[t] = 0;
  __syncthreads();
  int2 ebuf[8];
  #pragma unroll
  for (int it = 0; it < 8; it++){
    int i = ebase + it*1024 + t;
    int2 e = make_int2(s0[i], d0[i]);
    ebuf[it] = e;
    edges[i] = e;
    atomicAdd(&deg[e.y - gbase], 1);
  }
  __syncthreads();
  int vdeg = (t < 512) ? deg[t] : 0;
  int lane = t & 63, wid = t >> 6;
  int x = vdeg;
  #pragma unroll
  for (int off = 1; off < 64; off <<= 1){
    int y = __shfl_up(x, off);
    if (lane >= off) x += y;
  }
  if (t < 512 && lane == 63) wsum[wid] = x;
  __syncthreads();
  if (t < 512){
    int prefix = 0;
    #pragma unroll
    for (int wj = 0; wj < 8; wj++) prefix += (wj < wid) ? wsum[wj] : 0;
    int excl = x + prefix - vdeg;
    rowptr[gbase + t] = ebase + excl;
    cnt[gbase + t] = vdeg;
    cur[t] = excl;
    float dv = rsqrtf((float)vdeg + 1.f);
    dl[t] = dv;
    dinv[gbase + t] = dv;
  }
  __syncthreads();
  #pragma unroll
  for (int it = 0; it < 8; it++){
    int2 e = ebuf[it];
    int sl = e.x - gbase, dc = e.y - gbase;
    int pos = atomicAdd(&cur[dc], 1);
    csr[ebase + pos] = make_int2(e.x, __float_as_int(dl[sl]*dl[dc]));
  }
}

// Level-1 fused GEMM+gather; hl tile XOR-swizzled (validated r4-r9).
__global__ __launch_bounds__(512) void k_l1_fused(
    const float* __restrict__ x, const float* __restrict__ W1,
    const int2* __restrict__ csr, const int* __restrict__ rowptr,
    const int* __restrict__ cnt, const float* __restrict__ dinv,
    const float* __restrict__ b1, const float* __restrict__ Wp,
    float4* __restrict__ gout4, float* __restrict__ hp_part){
  extern __shared__ float hl[];   // 512 nodes x 32 feats = 64 KB
  int b = blockIdx.x;
  int xcd = b & 7, idx = b >> 3;
  int graph = xcd*8 + (idx >> 3);
  int sub = idx & 7;
  int qf = sub >> 1, half = sub & 1;
  int t = threadIdx.x;
  int gbase = graph*N0;
  int fp = t & 31;
  int f = qf*32 + fp;
  float wcol[10];
  #pragma unroll
  for (int k = 0; k < 10; k++) wcol[k] = W1[k*HID + f];
  for (int n = t >> 5; n < N0; n += 16){
    const float* xr = x + (gbase + n)*10;
    float acc = 0.f;
    #pragma unroll
    for (int k = 0; k < 10; k++) acc += xr[k]*wcol[k];
    hl[n*32 + ((((fp>>2)+n)&7)<<2) + (fp&3)] = acc;
  }
  __syncthreads();
  const float4* hl4 = (const float4*)hl;
  int l = t & 7, grp = t >> 3;
  float4 bb = ((const float4*)b1)[qf*8 + l];
  float4 wp = ((const float4*)Wp)[qf*8 + l];
  int n0 = half*256;
  for (int nl = n0 + grp; nl < n0 + 256; nl += 64){
    int node = gbase + nl;
    int start = rowptr[node], c = cnt[node];
    float4 acc = make_float4(0.f,0.f,0.f,0.f);
    int j = 0;
    for (; j + 4 <= c; j += 4){
      int2 e0 = csr[start+j],   e1 = csr[start+j+1];
      int2 e2 = csr[start+j+2], e3 = csr[start+j+3];
      float4 h0 = hl4[HSW(e0.x - gbase, l)];
      float4 h1 = hl4[HSW(e1.x - gbase, l)];
      float4 h2 = hl4[HSW(e2.x - gbase, l)];
      float4 h3 = hl4[HSW(e3.x - gbase, l)];
      float w0 = __int_as_float(e0.y), w1 = __int_as_float(e1.y);
      float w2 = __int_as_float(e2.y), w3 = __int_as_float(e3.y);
      acc.x += w0*h0.x + w1*h1.x + w2*h2.x + w3*h3.x;
      acc.y += w0*h0.y + w1*h1.y + w2*h2.y + w3*h3.y;
      acc.z += w0*h0.z + w1*h1.z + w2*h2.z + w3*h3.z;
      acc.w += w0*h0.w + w1*h1.w + w2*h2.w + w3*h3.w;
    }
    for (; j < c; j++){
      int2 e = csr[start + j];
      float wgt = __int_as_float(e.y);
      float4 hv = hl4[HSW(e.x - gbase, l)];
      acc.x += wgt*hv.x; acc.y += wgt*hv.y; acc.z += wgt*hv.z; acc.w += wgt*hv.w;
    }
    float di = dinv[node], dd = di*di;
    float4 hs = hl4[HSW(nl, l)];
    float4 v;
    v.x = fmaxf(acc.x + hs.x*dd + bb.x, 0.f);
    v.y = fmaxf(acc.y + hs.y*dd + bb.y, 0.f);
    v.z = fmaxf(acc.z + hs.z*dd + bb.z, 0.f);
    v.w = fmaxf(acc.w + hs.w*dd + bb.w, 0.f);
    gout4[node*32 + qf*8 + l] = v;
    float contrib = v.x*wp.x + v.y*wp.y + v.z*wp.z + v.w*wp.w;
    #pragma unroll
    for (int off = 4; off; off >>= 1) contrib += __shfl_down(contrib, off, 8);
    if (l == 0) hp_part[qf*32768 + node] = contrib;
  }
}

// mega1: score+sort over level-1, z store, si/sv export, relabel -> LOFF2.
// 1024-wide readout (r8 tweak set).
__global__ __launch_bounds__(1024) void k_mega1(
    const float4* __restrict__ gout4, const float* __restrict__ hppt,
    int2* __restrict__ csr, int* __restrict__ rowptr, int* __restrict__ cnt,
    float* __restrict__ dinv, const float* __restrict__ bp,
    int2* __restrict__ edges, int* __restrict__ sig, float* __restrict__ svg,
    float* __restrict__ z){
  __shared__ float sv[512];
  __shared__ int   si[512];
  __shared__ float hpl[512];
  __shared__ union UA {
    float spart[1024];
    struct { float4 pmx[32][32]; float4 psm[32][32]; } ro;
    struct { int map_[512]; int sb[512]; int cur[256]; } rl;
  } u;
  __shared__ float dl[256];
  __shared__ int   wsum[4];
  int g = (blockIdx.x & 7)*8 + (blockIdx.x >> 3);
  int t = threadIdx.x;
  int gbase = g*N0, ebase = g*EPG, gb2 = g*256;
  float bp0 = bp[0];
  int2 epre[8];
  #pragma unroll
  for (int it = 0; it < 8; it++) epre[it] = edges[ebase + it*1024 + t];
  if (t < 512){
    int node = gbase + t;
    hpl[t] = hppt[node] + hppt[32768+node] + hppt[65536+node] + hppt[98304+node];
  }
  __syncthreads();
  {  // split score, SPL=2
    int n = t & 511, p = t >> 9;
    int start = rowptr[gbase + n], c = cnt[gbase + n];
    int lo = (c*p) >> 1, hi = (c*(p+1)) >> 1;
    float a = 0.f;
    for (int j = lo; j < hi; j++){
      int2 e = csr[start + j];
      a += __int_as_float(e.y)*hpl[e.x - gbase];
    }
    u.spart[t] = a;
  }
  __syncthreads();
  float v = 0.f; int idx = t;
  if (t < 512){
    float a = u.spart[t] + u.spart[t + 512];
    float di = dinv[gbase + t];
    v = tanhf(a + hpl[t]*di*di + bp0);
  }
  __syncthreads();
  bitonic_sort(sv, si, v, idx, t, 512, t < 512);
  if (t < 256){ sig[g*512 + t] = si[t]; svg[g*512 + t] = sv[t]; }
  int l = t & 31, j0 = t >> 5;
  {
    float4 mx = make_float4(-INFINITY,-INFINITY,-INFINITY,-INFINITY);
    float4 sm = make_float4(0.f,0.f,0.f,0.f);
    for (int j = j0; j < 256; j += 32){
      float val = sv[j]; int row = si[j];
      float4 hv = gout4[(gbase + row)*32 + l];
      float4 o = make_float4(hv.x*val, hv.y*val, hv.z*val, hv.w*val);
      mx.x = fmaxf(mx.x, o.x); mx.y = fmaxf(mx.y, o.y);
      mx.z = fmaxf(mx.z, o.z); mx.w = fmaxf(mx.w, o.w);
      sm.x += o.x; sm.y += o.y; sm.z += o.z; sm.w += o.w;
    }
    u.ro.pmx[j0][l] = mx; u.ro.psm[j0][l] = sm;
  }
  __syncthreads();
  if (t < 32){
    float4 M = u.ro.pmx[0][t], S = u.ro.psm[0][t];
    #pragma unroll
    for (int q = 1; q < 32; q++){
      float4 m2 = u.ro.pmx[q][t], s2 = u.ro.psm[q][t];
      M.x = fmaxf(M.x, m2.x); M.y = fmaxf(M.y, m2.y);
      M.z = fmaxf(M.z, m2.z); M.w = fmaxf(M.w, m2.w);
      S.x += s2.x; S.y += s2.y; S.z += s2.z; S.w += s2.w;
    }
    float ki = 1.f/256.f;
    float* zp = z + g*256;
    zp[t*4+0] = M.x; zp[t*4+1] = M.y; zp[t*4+2] = M.z; zp[t*4+3] = M.w;
    zp[128+t*4+0] = S.x*ki; zp[128+t*4+1] = S.y*ki;
    zp[128+t*4+2] = S.z*ki; zp[128+t*4+3] = S.w*ki;
  }
  __syncthreads();
  relabel_pre(edges, csr, si, u.rl.map_, u.rl.sb, u.rl.cur, dl, wsum,
              rowptr, cnt, dinv, epre, t, 512, 256, gbase, gb2, ebase, LOFF2);
}

// k_lvl2: feature-split, 4 blocks/graph (r6 verbatim — best measured).
// Block (g,s) computes h2[:, s*32..s*32+31] (GEMM direct from L2-hot gout1,
// 32 KB HSW LDS), then gathers ALL 256 nodes for its slice.
__global__ __launch_bounds__(512) void k_lvl2(
    const float4* __restrict__ gout4,
    const int* __restrict__ sig, const float* __restrict__ svg,
    const float* __restrict__ W2, const float* __restrict__ b2,
    const float* __restrict__ Wp,
    const int2* __restrict__ csr, const int* __restrict__ rowptr,
    const int* __restrict__ cnt, const float* __restrict__ dinv,
    float4* __restrict__ g2out4, float* __restrict__ hp2p){
  __shared__ float hL[256*32];    // 32 KB slice tile
  int b = blockIdx.x;
  int jb = b & 63, s = b >> 6;
  int g = (jb & 7)*8 + (jb >> 3);
  int t = threadIdx.x;
  int gbase = g*N0, gb2 = g*256;
  float4* hL4 = (float4*)hL;
  {  // GEMM slice: 4 rows x 4 feats per thread
    int f4 = t & 7, rg = t >> 3;
    int rbase = rg*4;
    const float* Wb = W2 + s*32 + f4*4;
    int ri[4]; float rv[4];
    #pragma unroll
    for (int q = 0; q < 4; q++){
      ri[q] = sig[g*512 + rbase + q];
      rv[q] = svg[g*512 + rbase + q];
    }
    float4 acc[4];
    #pragma unroll
    for (int q = 0; q < 4; q++) acc[q] = make_float4(0.f,0.f,0.f,0.f);
    for (int i = 0; i < HID; i += 4){
      float4 w0 = *(const float4*)(Wb + (i+0)*HID);
      float4 w1 = *(const float4*)(Wb + (i+1)*HID);
      float4 w2 = *(const float4*)(Wb + (i+2)*HID);
      float4 w3 = *(const float4*)(Wb + (i+3)*HID);
      #pragma unroll
      for (int q = 0; q < 4; q++){
        float4 xv = gout4[(gbase + ri[q])*32 + (i>>2)];
        float vx = xv.x*rv[q], vy = xv.y*rv[q], vz = xv.z*rv[q], vw = xv.w*rv[q];
        acc[q].x += vx*w0.x + vy*w1.x + vz*w2.x + vw*w3.x;
        acc[q].y += vx*w0.y + vy*w1.y + vz*w2.y + vw*w3.y;
        acc[q].z += vx*w0.z + vy*w1.z + vz*w2.z + vw*w3.z;
        acc[q].w += vx*w0.w + vy*w1.w + vz*w2.w + vw*w3.w;
      }
    }
    #pragma unroll
    for (int q = 0; q < 4; q++) hL4[HSW(rbase+q, f4)] = acc[q];
  }
  __syncthreads();
  int l = t & 7, grpn = t >> 3;
  float4 bb = ((const float4*)b2)[s*8 + l];
  float4 wp = ((const float4*)Wp)[s*8 + l];
  for (int it = 0; it < 4; it++){
    int n = it*64 + grpn;
    int node = gb2 + n;
    int start = rowptr[LOFF2 + node], c = cnt[LOFF2 + node];
    float4 acc = make_float4(0.f,0.f,0.f,0.f);
    int j = 0;
    for (; j + 4 <= c; j += 4){
      int2 e0 = csr[start+j],   e1 = csr[start+j+1];
      int2 e2 = csr[start+j+2], e3 = csr[start+j+3];
      float4 h0 = hL4[HSW(e0.x - gb2, l)];
      float4 h1 = hL4[HSW(e1.x - gb2, l)];
      float4 h2 = hL4[HSW(e2.x - gb2, l)];
      float4 h3 = hL4[HSW(e3.x - gb2, l)];
      float w0 = __int_as_float(e0.y), w1 = __int_as_float(e1.y);
      float w2 = __int_as_float(e2.y), w3 = __int_as_float(e3.y);
      acc.x += w0*h0.x + w1*h1.x + w2*h2.x + w3*h3.x;
      acc.y += w0*h0.y + w1*h1.y + w2*h2.y + w3*h3.y;
      acc.z += w0*h0.z + w1*h1.z + w2*h2.z + w3*h3.z;
      acc.w += w0*h0.w + w1*h1.w + w2*h2.w + w3*h3.w;
    }
    for (; j < c; j++){
      int2 e = csr[start + j];
      float wgt = __int_as_float(e.y);
      float4 hv = hL4[HSW(e.x - gb2, l)];
      acc.x += wgt*hv.x; acc.y += wgt*hv.y; acc.z += wgt*hv.z; acc.w += wgt*hv.w;
    }
    float di = dinv[LOFF2 + node], dd = di*di;
    float4 hs = hL4[HSW(n, l)];
    float4 v;
    v.x = fmaxf(acc.x + hs.x*dd + bb.x, 0.f);
    v.y = fmaxf(acc.y + hs.y*dd + bb.y, 0.f);
    v.z = fmaxf(acc.z + hs.z*dd + bb.z, 0.f);
    v.w = fmaxf(acc.w + hs.w*dd + bb.w, 0.f);
    g2out4[node*32 + s*8 + l] = v;
    float contrib = v.x*wp.x + v.y*wp.y + v.z*wp.z + v.w*wp.w;
    #pragma unroll
    for (int off = 4; off; off >>= 1) contrib += __shfl_down(contrib, off, 8);
    if (l == 0) hp2p[s*16384 + node] = contrib;
  }
}

// mega2: score+sort over level-2, z accumulate, si/sv export, relabel -> LOFF3.
// 1024-wide readout (r8 tweak set).
__global__ __launch_bounds__(1024) void k_mega2(
    const float4* __restrict__ g2out4, const float* __restrict__ hp2p,
    int2* __restrict__ csr, int* __restrict__ rowptr, int* __restrict__ cnt,
    float* __restrict__ dinv, const float* __restrict__ bp,
    int2* __restrict__ edges, int* __restrict__ sig, float* __restrict__ svg,
    float* __restrict__ z){
  __shared__ float sv[256];
  __shared__ int   si[256];
  __shared__ float hpl[256];
  __shared__ union UB {
    float spart[1024];
    struct { float4 pmx[32][32]; float4 psm[32][32]; } ro;
    struct { int map_[256]; int sb[128]; int cur[128]; } rl;
  } u;
  __shared__ float dl[128];
  __shared__ int   wsum[4];
  int g = (blockIdx.x & 7)*8 + (blockIdx.x >> 3);
  int t = threadIdx.x;
  int gb2 = g*256, gb3 = g*128, ebase = g*EPG;
  float bp0 = bp[0];
  int2 epre[8];
  #pragma unroll
  for (int it = 0; it < 8; it++) epre[it] = edges[ebase + it*1024 + t];
  if (t < 256){
    int node = gb2 + t;
    hpl[t] = hp2p[node] + hp2p[16384+node] + hp2p[32768+node] + hp2p[49152+node];
  }
  __syncthreads();
  {  // split score, SPL=4
    int n = t & 255, p = t >> 8;
    int start = rowptr[LOFF2 + gb2 + n], c = cnt[LOFF2 + gb2 + n];
    int lo = (c*p) >> 2, hi = (c*(p+1)) >> 2;
    float a = 0.f;
    for (int j = lo; j < hi; j++){
      int2 e = csr[start + j];
      a += __int_as_float(e.y)*hpl[e.x - gb2];
    }
    u.spart[t] = a;
  }
  __syncthreads();
  float v = 0.f; int idx = t;
  if (t < 256){
    float a = u.spart[t] + u.spart[t+256] + u.spart[t+512] + u.spart[t+768];
    float di = dinv[LOFF2 + gb2 + t];
    v = tanhf(a + hpl[t]*di*di + bp0);
  }
  __syncthreads();
  bitonic_sort(sv, si, v, idx, t, 256, t < 256);
  if (t < 128){ sig[g*512 + t] = si[t]; svg[g*512 + t] = sv[t]; }
  int l = t & 31, j0 = t >> 5;
  {
    float4 mx = make_float4(-INFINITY,-INFINITY,-INFINITY,-INFINITY);
    float4 sm = make_float4(0.f,0.f,0.f,0.f);
    for (int j = j0; j < 128; j += 32){
      float val = sv[j]; int row = si[j];
      float4 hv = g2out4[(gb2 + row)*32 + l];
      float4 o = make_float4(hv.x*val, hv.y*val, hv.z*val, hv.w*val);
      mx.x = fmaxf(mx.x, o.x); mx.y = fmaxf(mx.y, o.y);
      mx.z = fmaxf(mx.z, o.z); mx.w = fmaxf(mx.w, o.w);
      sm.x += o.x; sm.y += o.y; sm.z += o.z; sm.w += o.w;
    }
    u.ro.pmx[j0][l] = mx; u.ro.psm[j0][l] = sm;
  }
  __syncthreads();
  if (t < 32){
    float4 M = u.ro.pmx[0][t], S = u.ro.psm[0][t];
    #pragma unroll
    for (int q = 1; q < 32; q++){
      float4 m2 = u.ro.pmx[q][t], s2 = u.ro.psm[q][t];
      M.x = fmaxf(M.x, m2.x); M.y = fmaxf(M.y, m2.y);
      M.z = fmaxf(M.z, m2.z); M.w = fmaxf(M.w, m2.w);
      S.x += s2.x; S.y += s2.y; S.z += s2.z; S.w += s2.w;
    }
    float ki = 1.f/128.f;
    float* zp = z + g*256;
    zp[t*4+0] += M.x; zp[t*4+1] += M.y; zp[t*4+2] += M.z; zp[t*4+3] += M.w;
    zp[128+t*4+0] += S.x*ki; zp[128+t*4+1] += S.y*ki;
    zp[128+t*4+2] += S.z*ki; zp[128+t*4+3] += S.w*ki;
  }
  __syncthreads();
  relabel_pre(edges, csr, si, u.rl.map_, u.rl.sb, u.rl.cur, dl, wsum,
              rowptr, cnt, dinv, epre, t, 256, 128, gb2, gb3, ebase, LOFF3);
}

// k_lvl3: feature-split, 4 blocks/graph (r6 verbatim); 128x32 slice GEMM
// (16 KB LDS), gather all 128 nodes; hp3 as 4 slice-partials.
__global__ __launch_bounds__(512) void k_lvl3(
    const float4* __restrict__ g2out4,
    const int* __restrict__ sig, const float* __restrict__ svg,
    const float* __restrict__ W3, const float* __restrict__ b3,
    const float* __restrict__ Wp,
    const int2* __restrict__ csr, const int* __restrict__ rowptr,
    const int* __restrict__ cnt, const float* __restrict__ dinv,
    float4* __restrict__ g3out4, float* __restrict__ hp3p){
  __shared__ float hL[128*32];    // 16 KB slice tile
  int b = blockIdx.x;
  int jb = b & 63, s = b >> 6;
  int g = (jb & 7)*8 + (jb >> 3);
  int t = threadIdx.x;
  int gb2 = g*256, gb3 = g*128;
  float4* hL4 = (float4*)hL;
  {  // GEMM slice: 2 rows x 4 feats per thread
    int f4 = t & 7, rg = t >> 3;
    int rbase = rg*2;
    const float* Wb = W3 + s*32 + f4*4;
    int ri[2]; float rv[2];
    #pragma unroll
    for (int q = 0; q < 2; q++){
      ri[q] = sig[g*512 + rbase + q];
      rv[q] = svg[g*512 + rbase + q];
    }
    float4 acc[2];
    #pragma unroll
    for (int q = 0; q < 2; q++) acc[q] = make_float4(0.f,0.f,0.f,0.f);
    for (int i = 0; i < HID; i += 4){
      float4 w0 = *(const float4*)(Wb + (i+0)*HID);
      float4 w1 = *(const float4*)(Wb + (i+1)*HID);
      float4 w2 = *(const float4*)(Wb + (i+2)*HID);
      float4 w3 = *(const float4*)(Wb + (i+3)*HID);
      #pragma unroll
      for (int q = 0; q < 2; q++){
        float4 xv = g2out4[(gb2 + ri[q])*32 + (i>>2)];
        float vx = xv.x*rv[q], vy = xv.y*rv[q], vz = xv.z*rv[q], vw = xv.w*rv[q];
        acc[q].x += vx*w0.x + vy*w1.x + vz*w2.x + vw*w3.x;
        acc[q].y += vx*w0.y + vy*w1.y + vz*w2.y + vw*w3.y;
        acc[q].z += vx*w0.z + vy*w1.z + vz*w2.z + vw*w3.z;
        acc[q].w += vx*w0.w + vy*w1.w + vz*w2.w + vw*w3.w;
      }
    }
    #pragma unroll
    for (int q = 0; q < 2; q++) hL4[HSW(rbase+q, f4)] = acc[q];
  }
  __syncthreads();
  int l = t & 7, grpn = t >> 3;
  float4 bb = ((const float4*)b3)[s*8 + l];
  float4 wp = ((const float4*)Wp)[s*8 + l];
  for (int it = 0; it < 2; it++){
    int n = it*64 + grpn;
    int node = gb3 + n;
    int start = rowptr[LOFF3 + node], c = cnt[LOFF3 + node];
    float4 acc = make_float4(0.f,0.f,0.f,0.f);
    int j = 0;
    for (; j + 4 <= c; j += 4){
      int2 e0 = csr[start+j],   e1 = csr[start+j+1];
      int2 e2 = csr[start+j+2], e3 = csr[start+j+3];
      float4 h0 = hL4[HSW(e0.x - gb3, l)];
      float4 h1 = hL4[HSW(e1.x - gb3, l)];
      float4 h2 = hL4[HSW(e2.x - gb3, l)];
      float4 h3 = hL4[HSW(e3.x - gb3, l)];
      float w0 = __int_as_float(e0.y), w1 = __int_as_float(e1.y);
      float w2 = __int_as_float(e2.y), w3 = __int_as_float(e3.y);
      acc.x += w0*h0.x + w1*h1.x + w2*h2.x + w3*h3.x;
      acc.y += w0*h0.y + w1*h1.y + w2*h2.y + w3*h3.y;
      acc.z += w0*h0.z + w1*h1.z + w2*h2.z + w3*h3.z;
      acc.w += w0*h0.w + w1*h1.w + w2*h2.w + w3*h3.w;
    }
    for (; j < c; j++){
      int2 e = csr[start + j];
      float wgt = __int_as_float(e.y);
      float4 hv = hL4[HSW(e.x - gb3, l)];
      acc.x += wgt*hv.x; acc.y += wgt*hv.y; acc.z += wgt*hv.z; acc.w += wgt*hv.w;
    }
    float di = dinv[LOFF3 + node], dd = di*di;
    float4 hs = hL4[HSW(n, l)];
    float4 v;
    v.x = fmaxf(acc.x + hs.x*dd + bb.x, 0.f);
    v.y = fmaxf(acc.y + hs.y*dd + bb.y, 0.f);
    v.z = fmaxf(acc.z + hs.z*dd + bb.z, 0.f);
    v.w = fmaxf(acc.w + hs.w*dd + bb.w, 0.f);
    g3out4[node*32 + s*8 + l] = v;
    float contrib = v.x*wp.x + v.y*wp.y + v.z*wp.z + v.w*wp.w;
    #pragma unroll
    for (int off = 4; off; off >>= 1) contrib += __shfl_down(contrib, off, 8);
    if (l == 0) hp3p[s*8192 + node] = contrib;
  }
}

// mega3: score+sort over level-3, readout finalize + MLP + log_softmax.
// 1024-wide readout (r8 tweak set).
__global__ __launch_bounds__(1024) void k_mega3(
    const float4* __restrict__ g3out4, const float* __restrict__ hp3p,
    const int2* __restrict__ csr, const int* __restrict__ rowptr,
    const int* __restrict__ cnt, const float* __restrict__ dinv,
    const float* __restrict__ bp, float* __restrict__ z,
    const float* __restrict__ L1W, const float* __restrict__ L1b,
    const float* __restrict__ L2W, const float* __restrict__ L2b,
    float* __restrict__ out){
  __shared__ float sv[128];
  __shared__ int   si[128];
  __shared__ float hpl[128];
  __shared__ union UC {
    float spart[1024];
    struct { float4 pmx[32][32]; float4 psm[32][32]; } ro;
  } u;
  __shared__ float zr[256];
  __shared__ float h1l[128];
  __shared__ float h2l[64];
  __shared__ float red[2];
  int g = (blockIdx.x & 7)*8 + (blockIdx.x >> 3);
  int t = threadIdx.x;
  int gb3 = g*128;
  float bp0 = bp[0];
  if (t < 128){
    int node = gb3 + t;
    hpl[t] = hp3p[node] + hp3p[8192+node] + hp3p[16384+node] + hp3p[24576+node];
  }
  __syncthreads();
  {  // split score, SPL=8
    int n = t & 127, p = t >> 7;
    int start = rowptr[LOFF3 + gb3 + n], c = cnt[LOFF3 + gb3 + n];
    int lo = (c*p) >> 3, hi = (c*(p+1)) >> 3;
    float a = 0.f;
    for (int j = lo; j < hi; j++){
      int2 e = csr[start + j];
      a += __int_as_float(e.y)*hpl[e.x - gb3];
    }
    u.spart[t] = a;
  }
  __syncthreads();
  float v = 0.f; int idx = t;
  if (t < 128){
    float a = 0.f;
    #pragma unroll
    for (int pp = 0; pp < 8; pp++) a += u.spart[t + pp*128];
    float di = dinv[LOFF3 + gb3 + t];
    v = tanhf(a + hpl[t]*di*di + bp0);
  }
  __syncthreads();
  bitonic_sort(sv, si, v, idx, t, 128, t < 128);
  int l = t & 31, j0 = t >> 5;
  {
    float4 mx = make_float4(-INFINITY,-INFINITY,-INFINITY,-INFINITY);
    float4 sm = make_float4(0.f,0.f,0.f,0.f);
    for (int j = j0; j < 64; j += 32){
      float val = sv[j]; int row = si[j];
      float4 hv = g3out4[(gb3 + row)*32 + l];
      float4 o = make_float4(hv.x*val, hv.y*val, hv.z*val, hv.w*val);
      mx.x = fmaxf(mx.x, o.x); mx.y = fmaxf(mx.y, o.y);
      mx.z = fmaxf(mx.z, o.z); mx.w = fmaxf(mx.w, o.w);
      sm.x += o.x; sm.y += o.y; sm.z += o.z; sm.w += o.w;
    }
    u.ro.pmx[j0][l] = mx; u.ro.psm[j0][l] = sm;
  }
  __syncthreads();
  if (t < 32){
    float4 M = u.ro.pmx[0][t], S = u.ro.psm[0][t];
    #pragma unroll
    for (int q = 1; q < 32; q++){
      float4 m2 = u.ro.pmx[q][t], s2 = u.ro.psm[q][t];
      M.x = fmaxf(M.x, m2.x); M.y = fmaxf(M.y, m2.y);
      M.z = fmaxf(M.z, m2.z); M.w = fmaxf(M.w, m2.w);
      S.x += s2.x; S.y += s2.y; S.z += s2.z; S.w += s2.w;
    }
    float ki = 1.f/64.f;
    float* zp = z + g*256;
    zr[t*4+0] = zp[t*4+0] + M.x; zr[t*4+1] = zp[t*4+1] + M.y;
    zr[t*4+2] = zp[t*4+2] + M.z; zr[t*4+3] = zp[t*4+3] + M.w;
    zr[128+t*4+0] = zp[128+t*4+0] + S.x*ki;
    zr[128+t*4+1] = zp[128+t*4+1] + S.y*ki;
    zr[128+t*4+2] = zp[128+t*4+2] + S.z*ki;
    zr[128+t*4+3] = zp[128+t*4+3] + S.w*ki;
  }
  __syncthreads();
  if (t < 128){
    float a = L1b[t];
    for (int i = 0; i < 256; i++) a += zr[i]*L1W[i*128 + t];
    h1l[t] = fmaxf(a, 0.f);
  }
  __syncthreads();
  if (t < 64){
    float a = L2b[t];
    for (int i = 0; i < 128; i++) a += h1l[i]*L2W[i*64 + t];
    h2l[t] = fmaxf(a, 0.f);
  }
  __syncthreads();
  if (t == 0){
    float mxv = -INFINITY;
    for (int i = 0; i < 64; i++) mxv = fmaxf(mxv, h2l[i]);
    float s = 0.f;
    for (int i = 0; i < 64; i++) s += expf(h2l[i] - mxv);
    red[0] = mxv; red[1] = logf(s);
  }
  __syncthreads();
  if (t < 64) out[g*64 + t] = h2l[t] - red[0] - red[1];
}

extern "C" void kernel_launch(void* const* d_in, const int* in_sizes, int n_in,
                              void* d_out, int out_size, void* d_ws, size_t ws_size,
                              hipStream_t stream){
  (void)in_sizes; (void)n_in; (void)out_size; (void)ws_size;
  const float* x0  = (const float*)d_in[0];
  const int*   s0  = (const int*)  d_in[1];
  const int*   d0  = (const int*)  d_in[2];
  const float* W1  = (const float*)d_in[3];  const float* b1 = (const float*)d_in[4];
  const float* W2  = (const float*)d_in[5];  const float* b2 = (const float*)d_in[6];
  const float* W3  = (const float*)d_in[7];  const float* b3 = (const float*)d_in[8];
  const float* Wp  = (const float*)d_in[9];  const float* bp = (const float*)d_in[10];
  const float* L1W = (const float*)d_in[11]; const float* L1b = (const float*)d_in[12];
  const float* L2W = (const float*)d_in[13]; const float* L2b = (const float*)d_in[14];
  float* out = (float*)d_out;

  // workspace layout (elements)
  float* w = (float*)d_ws;
  float* gout1 = w; w += 32768*HID;          // level-1 GCN output
  float* gout2 = w; w += 16384*HID;          // level-2 GCN output
  float* gout3 = w; w += 8192*HID;           // level-3 GCN output
  float* dinvv = w; w += 65536;              // levels via LOFF
  float* hppt  = w; w += 4*32768;            // L1 hp quarter-partials
  float* hp2p  = w; w += 4*16384;            // L2 hp slice-partials
  float* hp3p  = w; w += 4*8192;             // L3 hp slice-partials
  float* z     = w; w += BGR*256;
  float* svg   = w; w += 32768;
  int* sig     = (int*)w; w += 32768;
  int* cnt     = (int*)w; w += 65536;
  int* rowptr  = (int*)w; w += 65536;
  int2* edges  = (int2*)w; w += 2*E_TOT;
  int2* csr    = (int2*)w; w += 2*E_TOT;

  k_topo0<<<BGR, 1024, 0, stream>>>(s0, d0, edges, cnt, rowptr, dinvv, csr);
  k_l1_fused<<<512, 512, 65536, stream>>>(x0, W1, csr, rowptr, cnt, dinvv,
                                          b1, Wp, (float4*)gout1, hppt);
  k_mega1<<<BGR, 1024, 0, stream>>>((const float4*)gout1, hppt, csr, rowptr,
                                    cnt, dinvv, bp, edges, sig, svg, z);
  k_lvl2<<<4*BGR, 512, 0, stream>>>((const float4*)gout1, sig, svg, W2, b2, Wp,
                                    csr, rowptr, cnt, dinvv,
                                    (float4*)gout2, hp2p);
  k_mega2<<<BGR, 1024, 0, stream>>>((const float4*)gout2, hp2p, csr, rowptr,
                                    cnt, dinvv, bp, edges, sig, svg, z);
  k_lvl3<<<4*BGR, 512, 0, stream>>>((const float4*)gout2, sig, svg, W3, b3, Wp,
                                    csr, rowptr, cnt, dinvv,
                                    (float4*)gout3, hp3p);
  k_mega3<<<BGR, 1024, 0, stream>>>((const float4*)gout3, hp3p, csr, rowptr,
                                    cnt, dinvv, bp, z,
                                    L1W, L1b, L2W, L2b, out);
}